// Round 4
// baseline (383.836 us; speedup 1.0000x reference)
//
#include <hip/hip_runtime.h>
#include <stdint.h>

// NLinear: out[b,n,o] = sum_i x[b,n,i] * w[n,i,o] + bias[n,o]
// B=4096, N=200, D_IN=D_OUT=64.
//
// v5: contiguous-DRAM restructure. v4 post-mortem: kernel ~130us at ~2.9 TB/s
// while harness memsets hit 6.37 TB/s -> the 256B-piece/51.2KB-stride access
// pattern is DRAM-page-bound (~45% eff). Block now covers 4 consecutive n
// x 64 rows: all global loads/stores are 1KB-aligned contiguous segments.
// x: global_load_lds (async, dbuf, counted vmcnt) with source-side XOR
// swizzle (linear LDS dest) -> conflict-free ds_read_b128 fragments.
// out: written to LDS (own-wave column), cooperatively stored 1KB/instr.

#define B_DIM 4096
#define N_DIM 200
#define D 64
#define NCH 4            // consecutive n per block (1KB contiguous pieces)
#define RT 16            // rows per chunk (one 16-row MFMA fragment)
#define RPB 64           // rows per block
#define NCHUNK (RPB / RT)

typedef __attribute__((ext_vector_type(8))) _Float16 half8;   // 4 VGPR
typedef __attribute__((ext_vector_type(4))) float f32x4;

__device__ __forceinline__ void split8(const float4 a, const float4 b,
                                       half8& h, half8& l) {
  const float f[8] = {a.x, a.y, a.z, a.w, b.x, b.y, b.z, b.w};
#pragma unroll
  for (int j = 0; j < 8; ++j) {
    const _Float16 hh = (_Float16)f[j];          // RNE
    h[j] = hh;
    l[j] = (_Float16)(f[j] - (float)hh);         // residual, ~2^-11 rel
  }
}

// async 16B global->LDS (linear dest = uniform base + lane*16)
__device__ __forceinline__ void gl16(const float* g, float* l) {
  __builtin_amdgcn_global_load_lds(
      (const __attribute__((address_space(1))) void*)g,
      (__attribute__((address_space(3))) void*)l, 16, 0, 0);
}

// prep: w[n][k][o] -> split-fp16 per-lane A-operand fragments (unchanged
// from v4; proven correct). Fragment (n, ks, of): lane (kg,c), j=0..7 holds
// w[ks*32+kg*8+j][of*16+c].
__global__ __launch_bounds__(256)
void w_prep(const float* __restrict__ w,
            half8* __restrict__ wh, half8* __restrict__ wl) {
  const int n    = blockIdx.x;
  const int tid  = threadIdx.x;
  const int lane = tid & 63;
  const int g    = tid >> 6;
  const int c    = lane & 15;
  const int kg   = lane >> 4;
  const float* wn = w + (size_t)n * (D * D);
#pragma unroll
  for (int t = 0; t < 2; ++t) {
    const int combo = g * 2 + t;
    const int ks = combo >> 2;
    const int of = combo & 3;
    half8 h, l;
#pragma unroll
    for (int j = 0; j < 8; ++j) {
      const int k = ks * 32 + kg * 8 + j;
      const float v = wn[k * D + of * 16 + c];
      const _Float16 hh = (_Float16)v;
      h[j] = hh;
      l[j] = (_Float16)(v - (float)hh);
    }
    const size_t idx = ((size_t)(n * 2 + ks) * 4 + of) * 64 + lane;
    wh[idx] = h;
    wl[idx] = l;
  }
}

template <bool PREPPED>
__global__ __launch_bounds__(256, 4)
void nlinear_v5(const float* __restrict__ x,
                const float* __restrict__ w,
                const float* __restrict__ bias,
                const half8* __restrict__ wh,
                const half8* __restrict__ wl,
                float* __restrict__ out) {
  const int tid  = threadIdx.x;
  const int lane = tid & 63;
  const int wave = tid >> 6;       // = n-offset within the 4-n chunk
  const int c    = lane & 15;      // b-row within fragment
  const int kg   = lane >> 4;      // k-group
  const int nc   = blockIdx.y;     // n-chunk 0..49
  const int n    = nc * NCH + wave;
  const int r0   = blockIdx.x * RPB;
  const int sw   = c & 7;          // read-side swizzle

  // [2 buffers][16 rows][4n * 64 floats = 1KB/row]; out-tile reuses cur buf.
  __shared__ float xbuf[2][RT][NCH * D];   // 32 KB

  // ---- W fragments (A-operand), per-wave n.
  half8 Wh[2][4], Wl[2][4];
  if (PREPPED) {
#pragma unroll
    for (int ks = 0; ks < 2; ++ks)
#pragma unroll
      for (int of = 0; of < 4; ++of) {
        const size_t idx = ((size_t)(n * 2 + ks) * 4 + of) * 64 + lane;
        Wh[ks][of] = wh[idx];
        Wl[ks][of] = wl[idx];
      }
  } else {
    const float* wn = w + (size_t)n * (D * D);
#pragma unroll
    for (int ks = 0; ks < 2; ++ks)
#pragma unroll
      for (int of = 0; of < 4; ++of)
#pragma unroll
        for (int j = 0; j < 8; ++j) {
          const float v = wn[(ks * 32 + kg * 8 + j) * D + of * 16 + c];
          const _Float16 hh = (_Float16)v;
          Wh[ks][of][j] = hh;
          Wl[ks][of][j] = (_Float16)(v - (float)hh);
        }
  }

  float4 bv4[4];
#pragma unroll
  for (int of = 0; of < 4; ++of)
    bv4[of] = *(const float4*)(bias + (size_t)n * D + of * 16 + kg * 4);

  const size_t rstride = (size_t)N_DIM * D;                 // 12800 floats
  const float* xtile = x   + (size_t)r0 * rstride + (size_t)nc * (NCH * D);
  float*       otile = out + (size_t)r0 * rstride + (size_t)nc * (NCH * D);

  // Stage chunk ch into buf b: thread handles LDS-f4 i = tid + 256k.
  // LDS linear; global source piece pre-swizzled: p' = lane ^ (row&7).
  auto stage = [&](int ch, int b) {
    const float* base = xtile + (size_t)ch * RT * rstride;
    float* lbase = &xbuf[b][0][0];
#pragma unroll
    for (int k = 0; k < 4; ++k) {
      const int row = wave + 4 * k;                 // i>>6
      const int pp  = lane ^ (row & 7);             // source f4 within row
      gl16(base + (size_t)row * rstride + (size_t)pp * 4,
           lbase + (size_t)(tid + 256 * k) * 4);
    }
  };

  stage(0, 0);

  for (int ch = 0; ch < NCHUNK; ++ch) {
    const int cur = ch & 1;
    if (ch + 1 < NCHUNK) {
      stage(ch + 1, cur ^ 1);
      asm volatile("s_waitcnt vmcnt(4)" ::: "memory");   // cur's 4 retired
    } else {
      asm volatile("s_waitcnt vmcnt(0)" ::: "memory");
    }
    __builtin_amdgcn_sched_barrier(0);
    __builtin_amdgcn_s_barrier();
    __builtin_amdgcn_sched_barrier(0);

    // ---- compute from xbuf[cur]: lane reads row c, its wave's n-column.
    const float4* lp = (const float4*)&xbuf[cur][0][0];
    const int fbase = c * 64 + wave * 16 + kg * 2;
    const float4 v0 = lp[(fbase + 0) ^ sw];
    const float4 v1 = lp[(fbase + 1) ^ sw];
    const float4 v2 = lp[(fbase + 8) ^ sw];
    const float4 v3 = lp[(fbase + 9) ^ sw];

    half8 ah0, al0, ah1, al1;
    split8(v0, v1, ah0, al0);   // k = kg*8 + j
    split8(v2, v3, ah1, al1);   // k = 32 + kg*8 + j

    f32x4 acc[4];
#pragma unroll
    for (int of = 0; of < 4; ++of) {
      f32x4 t = {bv4[of].x, bv4[of].y, bv4[of].z, bv4[of].w};
      acc[of] = t;
    }
#pragma unroll
    for (int of = 0; of < 4; ++of) {
      acc[of] = __builtin_amdgcn_mfma_f32_16x16x32_f16(Wh[0][of], ah0, acc[of], 0, 0, 0);
      acc[of] = __builtin_amdgcn_mfma_f32_16x16x32_f16(Wl[0][of], ah0, acc[of], 0, 0, 0);
      acc[of] = __builtin_amdgcn_mfma_f32_16x16x32_f16(Wh[0][of], al0, acc[of], 0, 0, 0);
      acc[of] = __builtin_amdgcn_mfma_f32_16x16x32_f16(Wh[1][of], ah1, acc[of], 0, 0, 0);
      acc[of] = __builtin_amdgcn_mfma_f32_16x16x32_f16(Wl[1][of], ah1, acc[of], 0, 0, 0);
      acc[of] = __builtin_amdgcn_mfma_f32_16x16x32_f16(Wh[1][of], al1, acc[of], 0, 0, 0);
    }

    // ---- out-tile into xbuf[cur] (own-wave column of row c; no cross-wave
    // hazard; same-wave DS ordering covers read-before-write).
    f32x4* op = (f32x4*)&xbuf[cur][0][0];
#pragma unroll
    for (int of = 0; of < 4; ++of)
      op[(c * 64 + wave * 16 + of * 4 + kg) ^ sw] = acc[of];

    asm volatile("s_waitcnt lgkmcnt(0)" ::: "memory");
    __builtin_amdgcn_sched_barrier(0);
    __builtin_amdgcn_s_barrier();
    __builtin_amdgcn_sched_barrier(0);

    // ---- cooperative contiguous store: 1KB per instr per wave-k.
    const float4* rp = (const float4*)&xbuf[cur][0][0];
#pragma unroll
    for (int k = 0; k < 4; ++k) {
      const int row = wave + 4 * k;
      const float4 vv = rp[(tid + 256 * k) ^ (row & 7)];
      *(float4*)(otile + (size_t)(ch * RT + row) * rstride + lane * 4) = vv;
    }

    // reads of cur done (forced by store data-dep) before cur is restaged.
    __builtin_amdgcn_sched_barrier(0);
    __builtin_amdgcn_s_barrier();
    __builtin_amdgcn_sched_barrier(0);
  }
}

extern "C" void kernel_launch(void* const* d_in, const int* in_sizes, int n_in,
                              void* d_out, int out_size, void* d_ws, size_t ws_size,
                              hipStream_t stream) {
  const float* x    = (const float*)d_in[0];   // (4096, 200, 64)
  const float* w    = (const float*)d_in[1];   // (1, 200, 64, 64)
  const float* bias = (const float*)d_in[2];   // (1, 200, 64)
  float*       out  = (float*)d_out;           // (4096, 200, 64)

  const size_t NFRAGS = (size_t)N_DIM * 2 * 4 * 64;      // 102400 fragments
  const size_t NEED   = NFRAGS * 16 * 2;                 // 3,276,800 B

  dim3 grid(B_DIM / RPB, N_DIM / NCH);                   // 64 x 50 = 3200
  if (d_ws && ws_size >= NEED) {
    half8* whp = (half8*)d_ws;
    half8* wlp = whp + NFRAGS;
    w_prep<<<dim3(N_DIM), dim3(256), 0, stream>>>(w, whp, wlp);
    nlinear_v5<true><<<grid, dim3(256), 0, stream>>>(x, w, bias, whp, wlp, out);
  } else {
    nlinear_v5<false><<<grid, dim3(256), 0, stream>>>(x, w, bias, nullptr, nullptr, out);
  }
}